// Round 1
// baseline (2756.694 us; speedup 1.0000x reference)
//
#include <hip/hip_runtime.h>
#include <math.h>

static constexpr float kSigma2 = 0.05f * 0.05f;

__device__ __forceinline__ int load_idx(const void* ei, long long j, int is64) {
    if (is64) return (int)(((const long long*)ei)[j]);
    return ((const int*)ei)[j];
}

// Detect whether edge_index is int64 (all odd int32 words zero) or int32.
// nz must be pre-zeroed; nz!=0 => int32 encoding.
__global__ void k_detect(const int* __restrict__ ei32, int E, int* __restrict__ nz) {
    int t = threadIdx.x;
    int lim = E < 2048 ? E : 2048;
    int acc = 0;
    for (int k = t; k < lim; k += blockDim.x) acc |= ei32[2 * k + 1];
    if (acc) atomicOr(nz, 1);
}

__global__ void k_accum1(const void* __restrict__ ei,
                         const float* __restrict__ src,
                         const float* __restrict__ tgt,
                         float* __restrict__ cnt,
                         float* __restrict__ ssum,
                         float* __restrict__ tsum,
                         const int* __restrict__ nz,
                         int E, int N) {
    int e = blockIdx.x * blockDim.x + threadIdx.x;
    if (e >= E) return;
    int is64 = (*nz == 0);
    int d = load_idx(ei, e, is64);
    int n = load_idx(ei, (long long)E + e, is64);
    if ((unsigned)d >= (unsigned)N || (unsigned)n >= (unsigned)N) return;
    atomicAdd(&cnt[d], 1.0f);
    atomicAdd(&ssum[3 * d + 0], src[3 * n + 0]);
    atomicAdd(&ssum[3 * d + 1], src[3 * n + 1]);
    atomicAdd(&ssum[3 * d + 2], src[3 * n + 2]);
    atomicAdd(&tsum[3 * d + 0], tgt[3 * n + 0]);
    atomicAdd(&tsum[3 * d + 1], tgt[3 * n + 1]);
    atomicAdd(&tsum[3 * d + 2], tgt[3 * n + 2]);
}

__global__ void k_centers(float* __restrict__ cnt,
                          float* __restrict__ ssum,
                          float* __restrict__ tsum, int N) {
    int i = blockIdx.x * blockDim.x + threadIdx.x;
    if (i >= N) return;
    float inv = 1.0f / fmaxf(cnt[i], 1.0f);
    ssum[3 * i + 0] *= inv;
    ssum[3 * i + 1] *= inv;
    ssum[3 * i + 2] *= inv;
    tsum[3 * i + 0] *= inv;
    tsum[3 * i + 1] *= inv;
    tsum[3 * i + 2] *= inv;
}

__global__ void k_accum2(const void* __restrict__ ei,
                         const float* __restrict__ src,
                         const float* __restrict__ tgt,
                         const float* __restrict__ ew,
                         const float* __restrict__ sc,
                         const float* __restrict__ tc,
                         float* __restrict__ Mm,
                         const int* __restrict__ nz,
                         int E, int N) {
    int e = blockIdx.x * blockDim.x + threadIdx.x;
    if (e >= E) return;
    int is64 = (*nz == 0);
    int d = load_idx(ei, e, is64);
    int n = load_idx(ei, (long long)E + e, is64);
    if ((unsigned)d >= (unsigned)N || (unsigned)n >= (unsigned)N) return;
    float w = ew[e];
    float a0 = (src[3 * n + 0] - sc[3 * d + 0]) * w;
    float a1 = (src[3 * n + 1] - sc[3 * d + 1]) * w;
    float a2 = (src[3 * n + 2] - sc[3 * d + 2]) * w;
    float b0 = tgt[3 * n + 0] - tc[3 * d + 0];
    float b1 = tgt[3 * n + 1] - tc[3 * d + 1];
    float b2 = tgt[3 * n + 2] - tc[3 * d + 2];
    float* Md = Mm + 9 * (long long)d;
    atomicAdd(Md + 0, a0 * b0); atomicAdd(Md + 1, a0 * b1); atomicAdd(Md + 2, a0 * b2);
    atomicAdd(Md + 3, a1 * b0); atomicAdd(Md + 4, a1 * b1); atomicAdd(Md + 5, a1 * b2);
    atomicAdd(Md + 6, a2 * b0); atomicAdd(Md + 7, a2 * b1); atomicAdd(Md + 8, a2 * b2);
}

// Per-node 3x3 Kabsch via Jacobi eigendecomposition of M^T M (fp64).
__global__ void k_kabsch(const float* __restrict__ Mm,
                         const float* __restrict__ sc,
                         const float* __restrict__ tc,
                         float* __restrict__ Rout,
                         float* __restrict__ Tout,
                         int N) {
    int i = blockIdx.x * blockDim.x + threadIdx.x;
    if (i >= N) return;

    double M[3][3];
#pragma unroll
    for (int r = 0; r < 3; ++r)
#pragma unroll
        for (int c = 0; c < 3; ++c)
            M[r][c] = (double)Mm[9 * (long long)i + 3 * r + c];

    double frob2 = 0.0;
#pragma unroll
    for (int r = 0; r < 3; ++r)
#pragma unroll
        for (int c = 0; c < 3; ++c) frob2 += M[r][c] * M[r][c];

    double Rm[3][3] = {{1, 0, 0}, {0, 1, 0}, {0, 0, 1}};

    if (frob2 > 1e-80) {
        // A = M^T M (symmetric PSD)
        double A[3][3];
#pragma unroll
        for (int r = 0; r < 3; ++r)
#pragma unroll
            for (int c = 0; c < 3; ++c) {
                double s = 0.0;
#pragma unroll
                for (int k = 0; k < 3; ++k) s += M[k][r] * M[k][c];
                A[r][c] = s;
            }
        double V[3][3] = {{1, 0, 0}, {0, 1, 0}, {0, 0, 1}};
        const int PL[3] = {0, 0, 1};
        const int QL[3] = {1, 2, 2};
        for (int sweep = 0; sweep < 15; ++sweep) {
            double off = fabs(A[0][1]) + fabs(A[0][2]) + fabs(A[1][2]);
            if (off == 0.0) break;
            for (int pi = 0; pi < 3; ++pi) {
                int p = PL[pi], q = QL[pi], r3 = 3 - p - q;
                double apq = A[p][q];
                if (apq == 0.0) continue;
                double theta = (A[q][q] - A[p][p]) / (2.0 * apq);
                double t = copysign(1.0, theta) / (fabs(theta) + sqrt(theta * theta + 1.0));
                double c = 1.0 / sqrt(t * t + 1.0);
                double s = t * c;
                double app = A[p][p], aqq = A[q][q];
                A[p][p] = app - t * apq;
                A[q][q] = aqq + t * apq;
                A[p][q] = 0.0; A[q][p] = 0.0;
                double arp = A[r3][p], arq = A[r3][q];
                A[r3][p] = c * arp - s * arq; A[p][r3] = A[r3][p];
                A[r3][q] = s * arp + c * arq; A[q][r3] = A[r3][q];
#pragma unroll
                for (int k = 0; k < 3; ++k) {
                    double vp = V[k][p], vq = V[k][q];
                    V[k][p] = c * vp - s * vq;
                    V[k][q] = s * vp + c * vq;
                }
            }
        }
        double lam0 = A[0][0], lam1 = A[1][1], lam2 = A[2][2];
        int id0 = 0, id1 = 1, id2 = 2, tt;
        double lam[3] = {lam0, lam1, lam2};
        if (lam[id0] < lam[id1]) { tt = id0; id0 = id1; id1 = tt; }
        if (lam[id0] < lam[id2]) { tt = id0; id0 = id2; id2 = tt; }
        if (lam[id1] < lam[id2]) { tt = id1; id1 = id2; id2 = tt; }
        double v1[3] = {V[0][id0], V[1][id0], V[2][id0]};
        double v2[3] = {V[0][id1], V[1][id1], V[2][id1]};
        double v3[3] = {V[0][id2], V[1][id2], V[2][id2]};

        double b1[3], b2[3];
#pragma unroll
        for (int r = 0; r < 3; ++r) {
            b1[r] = M[r][0] * v1[0] + M[r][1] * v1[1] + M[r][2] * v1[2];
            b2[r] = M[r][0] * v2[0] + M[r][1] * v2[1] + M[r][2] * v2[2];
        }
        double n1 = sqrt(b1[0] * b1[0] + b1[1] * b1[1] + b1[2] * b1[2]);
        if (n1 > 1e-150) {
            double u1[3] = {b1[0] / n1, b1[1] / n1, b1[2] / n1};
            double dot = u1[0] * b2[0] + u1[1] * b2[1] + u1[2] * b2[2];
            double w2[3] = {b2[0] - dot * u1[0], b2[1] - dot * u1[1], b2[2] - dot * u1[2]};
            double n2 = sqrt(w2[0] * w2[0] + w2[1] * w2[1] + w2[2] * w2[2]);
            double u2[3];
            if (n2 > n1 * 1e-12) {
                u2[0] = w2[0] / n2; u2[1] = w2[1] / n2; u2[2] = w2[2] / n2;
            } else {
                double ex0 = (fabs(u1[0]) < 0.9) ? 1.0 : 0.0;
                double ex1 = 1.0 - ex0;
                // u2 = normalize(cross(u1, e))
                double cx = u1[1] * 0.0 - u1[2] * ex1;
                double cy = u1[2] * ex0 - u1[0] * 0.0;
                double cz = u1[0] * ex1 - u1[1] * ex0;
                double cn = sqrt(cx * cx + cy * cy + cz * cz);
                u2[0] = cx / cn; u2[1] = cy / cn; u2[2] = cz / cn;
            }
            double u3[3] = {u1[1] * u2[2] - u1[2] * u2[1],
                            u1[2] * u2[0] - u1[0] * u2[2],
                            u1[0] * u2[1] - u1[1] * u2[0]};
            // det of sorted-column V
            double dV = v1[0] * (v2[1] * v3[2] - v2[2] * v3[1])
                      - v1[1] * (v2[0] * v3[2] - v2[2] * v3[0])
                      + v1[2] * (v2[0] * v3[1] - v2[1] * v3[0]);
            dV = (dV >= 0.0) ? 1.0 : -1.0;
#pragma unroll
            for (int r = 0; r < 3; ++r)
#pragma unroll
                for (int c = 0; c < 3; ++c)
                    Rm[r][c] = u1[r] * v1[c] + u2[r] * v2[c] + dV * u3[r] * v3[c];
        }
    }

    double s0 = (double)sc[3 * i + 0], s1 = (double)sc[3 * i + 1], s2 = (double)sc[3 * i + 2];
    double t0 = (double)tc[3 * i + 0], t1 = (double)tc[3 * i + 1], t2 = (double)tc[3 * i + 2];
#pragma unroll
    for (int r = 0; r < 3; ++r)
#pragma unroll
        for (int c = 0; c < 3; ++c)
            Rout[9 * (long long)i + 3 * r + c] = (float)Rm[r][c];
    Tout[3 * i + 0] = (float)(t0 - (Rm[0][0] * s0 + Rm[0][1] * s1 + Rm[0][2] * s2));
    Tout[3 * i + 1] = (float)(t1 - (Rm[1][0] * s0 + Rm[1][1] * s1 + Rm[1][2] * s2));
    Tout[3 * i + 2] = (float)(t2 - (Rm[2][0] * s0 + Rm[2][1] * s1 + Rm[2][2] * s2));
}

__global__ void k_weights(const void* __restrict__ ei,
                          const float* __restrict__ src,
                          const float* __restrict__ tgt,
                          const float* __restrict__ R,
                          const float* __restrict__ T,
                          float* __restrict__ wout,
                          const int* __restrict__ nz,
                          int E, int N) {
    int e = blockIdx.x * blockDim.x + threadIdx.x;
    if (e >= E) return;
    int is64 = (*nz == 0);
    int n = load_idx(ei, (long long)E + e, is64);
    float w = 1.0f;
    if ((unsigned)n < (unsigned)N) {
        float p0 = src[3 * n + 0], p1 = src[3 * n + 1], p2 = src[3 * n + 2];
        float q0 = tgt[3 * n + 0], q1 = tgt[3 * n + 1], q2 = tgt[3 * n + 2];
        const float* Rn = R + 9 * (long long)n;
        const float* Tn = T + 3 * (long long)n;
        float x0 = Rn[0] * p0 + Rn[1] * p1 + Rn[2] * p2 + Tn[0];
        float x1 = Rn[3] * p0 + Rn[4] * p1 + Rn[5] * p2 + Tn[1];
        float x2 = Rn[6] * p0 + Rn[7] * p1 + Rn[8] * p2 + Tn[2];
        float d0 = x0 - q0, d1 = x1 - q1, d2 = x2 - q2;
        float dd = d0 * d0 + d1 * d1 + d2 * d2;
        w = kSigma2 / (dd + kSigma2);
    }
    wout[e] = w;
}

extern "C" void kernel_launch(void* const* d_in, const int* in_sizes, int n_in,
                              void* d_out, int out_size, void* d_ws, size_t ws_size,
                              hipStream_t stream) {
    const float* src = (const float*)d_in[0];
    const float* tgt = (const float*)d_in[1];
    const void* ei = d_in[2];
    const float* ew = (const float*)d_in[3];
    int N = in_sizes[0] / 3;
    int E = in_sizes[3];

    float* out = (float*)d_out;
    float* Rout = out;
    float* Tout = out + (size_t)9 * N;
    float* Wout = out + (size_t)12 * N;

    float* cnt = (float*)d_ws;
    float* ssum = cnt + N;
    float* tsum = ssum + 3 * (size_t)N;
    float* Mm = tsum + 3 * (size_t)N;
    int* nz = (int*)(Mm + 9 * (size_t)N);

    size_t ws_bytes = (size_t)16 * N * sizeof(float) + 16;
    hipMemsetAsync(d_ws, 0, ws_bytes, stream);

    k_detect<<<1, 256, 0, stream>>>((const int*)ei, E, nz);

    int eb = (E + 255) / 256;
    int nb = (N + 255) / 256;
    k_accum1<<<eb, 256, 0, stream>>>(ei, src, tgt, cnt, ssum, tsum, nz, E, N);
    k_centers<<<nb, 256, 0, stream>>>(cnt, ssum, tsum, N);
    k_accum2<<<eb, 256, 0, stream>>>(ei, src, tgt, ew, ssum, tsum, Mm, nz, E, N);
    k_kabsch<<<nb, 256, 0, stream>>>(Mm, ssum, tsum, Rout, Tout, N);
    k_weights<<<eb, 256, 0, stream>>>(ei, src, tgt, Rout, Tout, Wout, nz, E, N);
}

// Round 2
// 682.434 us; speedup vs baseline: 4.0395x; 4.0395x over previous
//
#include <hip/hip_runtime.h>
#include <math.h>

static constexpr float kSigma2 = 0.05f * 0.05f;

__device__ __forceinline__ int load_idx(const void* ei, long long j, int is64) {
    if (is64) return (int)(((const long long*)ei)[j]);
    return ((const int*)ei)[j];
}

// Detect whether edge_index is int64 (all odd int32 words zero) or int32.
__global__ void k_detect(const int* __restrict__ ei32, int E, int* __restrict__ nz) {
    int t = threadIdx.x;
    int lim = E < 2048 ? E : 2048;
    int acc = 0;
    for (int k = t; k < lim; k += blockDim.x) acc |= ei32[2 * k + 1];
    if (acc) atomicOr(nz, 1);
}

// ---------------- shared Kabsch core (fp64, Jacobi on M^T M) ----------------
__device__ void kabsch_from_M(const double M[3][3], double Rm[3][3]) {
    Rm[0][0] = 1; Rm[0][1] = 0; Rm[0][2] = 0;
    Rm[1][0] = 0; Rm[1][1] = 1; Rm[1][2] = 0;
    Rm[2][0] = 0; Rm[2][1] = 0; Rm[2][2] = 1;

    double frob2 = 0.0;
#pragma unroll
    for (int r = 0; r < 3; ++r)
#pragma unroll
        for (int c = 0; c < 3; ++c) frob2 += M[r][c] * M[r][c];
    if (frob2 <= 1e-80) return;

    double A[3][3];
#pragma unroll
    for (int r = 0; r < 3; ++r)
#pragma unroll
        for (int c = 0; c < 3; ++c) {
            double s = 0.0;
#pragma unroll
            for (int k = 0; k < 3; ++k) s += M[k][r] * M[k][c];
            A[r][c] = s;
        }
    double V[3][3] = {{1, 0, 0}, {0, 1, 0}, {0, 0, 1}};
    const int PL[3] = {0, 0, 1};
    const int QL[3] = {1, 2, 2};
    for (int sweep = 0; sweep < 15; ++sweep) {
        double off = fabs(A[0][1]) + fabs(A[0][2]) + fabs(A[1][2]);
        if (off == 0.0) break;
        for (int pi = 0; pi < 3; ++pi) {
            int p = PL[pi], q = QL[pi], r3 = 3 - p - q;
            double apq = A[p][q];
            if (apq == 0.0) continue;
            double theta = (A[q][q] - A[p][p]) / (2.0 * apq);
            double t = copysign(1.0, theta) / (fabs(theta) + sqrt(theta * theta + 1.0));
            double c = 1.0 / sqrt(t * t + 1.0);
            double s = t * c;
            A[p][p] -= t * apq;
            A[q][q] += t * apq;
            A[p][q] = 0.0; A[q][p] = 0.0;
            double arp = A[r3][p], arq = A[r3][q];
            A[r3][p] = c * arp - s * arq; A[p][r3] = A[r3][p];
            A[r3][q] = s * arp + c * arq; A[q][r3] = A[r3][q];
#pragma unroll
            for (int k = 0; k < 3; ++k) {
                double vp = V[k][p], vq = V[k][q];
                V[k][p] = c * vp - s * vq;
                V[k][q] = s * vp + c * vq;
            }
        }
    }
    double lam[3] = {A[0][0], A[1][1], A[2][2]};
    int id0 = 0, id1 = 1, id2 = 2, tt;
    if (lam[id0] < lam[id1]) { tt = id0; id0 = id1; id1 = tt; }
    if (lam[id0] < lam[id2]) { tt = id0; id0 = id2; id2 = tt; }
    if (lam[id1] < lam[id2]) { tt = id1; id1 = id2; id2 = tt; }
    double v1[3] = {V[0][id0], V[1][id0], V[2][id0]};
    double v2[3] = {V[0][id1], V[1][id1], V[2][id1]};
    double v3[3] = {V[0][id2], V[1][id2], V[2][id2]};

    double b1[3], b2[3];
#pragma unroll
    for (int r = 0; r < 3; ++r) {
        b1[r] = M[r][0] * v1[0] + M[r][1] * v1[1] + M[r][2] * v1[2];
        b2[r] = M[r][0] * v2[0] + M[r][1] * v2[1] + M[r][2] * v2[2];
    }
    double n1 = sqrt(b1[0] * b1[0] + b1[1] * b1[1] + b1[2] * b1[2]);
    if (n1 <= 1e-150) return;
    double u1[3] = {b1[0] / n1, b1[1] / n1, b1[2] / n1};
    double dot = u1[0] * b2[0] + u1[1] * b2[1] + u1[2] * b2[2];
    double w2[3] = {b2[0] - dot * u1[0], b2[1] - dot * u1[1], b2[2] - dot * u1[2]};
    double n2 = sqrt(w2[0] * w2[0] + w2[1] * w2[1] + w2[2] * w2[2]);
    double u2[3];
    if (n2 > n1 * 1e-12) {
        u2[0] = w2[0] / n2; u2[1] = w2[1] / n2; u2[2] = w2[2] / n2;
    } else {
        double ex0 = (fabs(u1[0]) < 0.9) ? 1.0 : 0.0;
        double ex1 = 1.0 - ex0;
        double cx = u1[1] * 0.0 - u1[2] * ex1;
        double cy = u1[2] * ex0 - u1[0] * 0.0;
        double cz = u1[0] * ex1 - u1[1] * ex0;
        double cn = sqrt(cx * cx + cy * cy + cz * cz);
        u2[0] = cx / cn; u2[1] = cy / cn; u2[2] = cz / cn;
    }
    double u3[3] = {u1[1] * u2[2] - u1[2] * u2[1],
                    u1[2] * u2[0] - u1[0] * u2[2],
                    u1[0] * u2[1] - u1[1] * u2[0]};
    double dV = v1[0] * (v2[1] * v3[2] - v2[2] * v3[1])
              - v1[1] * (v2[0] * v3[2] - v2[2] * v3[0])
              + v1[2] * (v2[0] * v3[1] - v2[1] * v3[0]);
    dV = (dV >= 0.0) ? 1.0 : -1.0;
#pragma unroll
    for (int r = 0; r < 3; ++r)
#pragma unroll
        for (int c = 0; c < 3; ++c)
            Rm[r][c] = u1[r] * v1[c] + u2[r] * v2[c] + dV * u3[r] * v3[c];
}

// ---------------- sort-based path ----------------

__global__ void k_hist(const void* __restrict__ ei, int* __restrict__ cnt,
                       const int* __restrict__ nz, int E, int N) {
    int e = blockIdx.x * blockDim.x + threadIdx.x;
    if (e >= E) return;
    int is64 = (*nz == 0);
    int d = load_idx(ei, e, is64);
    if ((unsigned)d < (unsigned)N) atomicAdd(&cnt[d], 1);
}

__global__ void k_scan1(const int* __restrict__ cnt, int* __restrict__ off,
                        int* __restrict__ partials, int N) {
    __shared__ int sm[256];
    int tid = threadIdx.x;
    int i = blockIdx.x * 256 + tid;
    int v = (i < N) ? cnt[i] : 0;
    sm[tid] = v;
    __syncthreads();
    for (int s = 1; s < 256; s <<= 1) {
        int t = (tid >= s) ? sm[tid - s] : 0;
        __syncthreads();
        sm[tid] += t;
        __syncthreads();
    }
    int incl = sm[tid];
    if (i < N) off[i] = incl - v;
    if (tid == 255) partials[blockIdx.x] = incl;
}

__global__ void k_scan2(int* __restrict__ partials, int nb) {
    __shared__ int sm[512];
    int tid = threadIdx.x;
    int v = (tid < nb) ? partials[tid] : 0;
    sm[tid] = v;
    __syncthreads();
    for (int s = 1; s < 512; s <<= 1) {
        int t = (tid >= s) ? sm[tid - s] : 0;
        __syncthreads();
        sm[tid] += t;
        __syncthreads();
    }
    if (tid < nb) partials[tid] = sm[tid] - v;  // exclusive
}

__global__ void k_scan3(int* __restrict__ off, int* __restrict__ cur,
                        const int* __restrict__ partials, int N) {
    int i = blockIdx.x * blockDim.x + threadIdx.x;
    if (i >= N) return;
    int o = off[i] + partials[i >> 8];
    off[i] = o;
    cur[i] = o;
}

__global__ void k_scatter(const void* __restrict__ ei,
                          const float* __restrict__ ew,
                          int* __restrict__ cur,
                          int2* __restrict__ sedge,
                          const int* __restrict__ nz, int E, int N) {
    int e = blockIdx.x * blockDim.x + threadIdx.x;
    if (e >= E) return;
    int is64 = (*nz == 0);
    int d = load_idx(ei, e, is64);
    int n = load_idx(ei, (long long)E + e, is64);
    if ((unsigned)d >= (unsigned)N || (unsigned)n >= (unsigned)N) return;
    int p = atomicAdd(&cur[d], 1);
    int2 pk;
    pk.x = n;
    pk.y = __float_as_int(ew[e]);
    sedge[p] = pk;
}

// One thread per node: sums -> centers -> covariance M -> Kabsch -> R, T.
__global__ void k_node(const int* __restrict__ off,
                       const int* __restrict__ cur,
                       const int2* __restrict__ sedge,
                       const float* __restrict__ src,
                       const float* __restrict__ tgt,
                       float* __restrict__ Rout,
                       float* __restrict__ Tout, int N) {
    int i = blockIdx.x * blockDim.x + threadIdx.x;
    if (i >= N) return;
    int start = off[i];
    int end = cur[i];  // off[i] + actual count

    float c = 0.0f;
    float s0 = 0, s1 = 0, s2 = 0, t0 = 0, t1 = 0, t2 = 0;
    for (int j = start; j < end; ++j) {
        int n = sedge[j].x;
        s0 += src[3 * n + 0]; s1 += src[3 * n + 1]; s2 += src[3 * n + 2];
        t0 += tgt[3 * n + 0]; t1 += tgt[3 * n + 1]; t2 += tgt[3 * n + 2];
        c += 1.0f;
    }
    float inv = 1.0f / fmaxf(c, 1.0f);
    float scx = s0 * inv, scy = s1 * inv, scz = s2 * inv;
    float tcx = t0 * inv, tcy = t1 * inv, tcz = t2 * inv;

    float m00 = 0, m01 = 0, m02 = 0, m10 = 0, m11 = 0, m12 = 0, m20 = 0, m21 = 0, m22 = 0;
    for (int j = start; j < end; ++j) {
        int2 pk = sedge[j];
        int n = pk.x;
        float w = __int_as_float(pk.y);
        float a0 = (src[3 * n + 0] - scx) * w;
        float a1 = (src[3 * n + 1] - scy) * w;
        float a2 = (src[3 * n + 2] - scz) * w;
        float b0 = tgt[3 * n + 0] - tcx;
        float b1 = tgt[3 * n + 1] - tcy;
        float b2 = tgt[3 * n + 2] - tcz;
        m00 += a0 * b0; m01 += a0 * b1; m02 += a0 * b2;
        m10 += a1 * b0; m11 += a1 * b1; m12 += a1 * b2;
        m20 += a2 * b0; m21 += a2 * b1; m22 += a2 * b2;
    }

    double M[3][3] = {{m00, m01, m02}, {m10, m11, m12}, {m20, m21, m22}};
    double Rm[3][3];
    kabsch_from_M(M, Rm);

#pragma unroll
    for (int r = 0; r < 3; ++r)
#pragma unroll
        for (int cc = 0; cc < 3; ++cc)
            Rout[9 * (long long)i + 3 * r + cc] = (float)Rm[r][cc];
    Tout[3 * i + 0] = (float)((double)tcx - (Rm[0][0] * scx + Rm[0][1] * scy + Rm[0][2] * scz));
    Tout[3 * i + 1] = (float)((double)tcy - (Rm[1][0] * scx + Rm[1][1] * scy + Rm[1][2] * scz));
    Tout[3 * i + 2] = (float)((double)tcz - (Rm[2][0] * scx + Rm[2][1] * scy + Rm[2][2] * scz));
}

__global__ void k_weights(const void* __restrict__ ei,
                          const float* __restrict__ src,
                          const float* __restrict__ tgt,
                          const float* __restrict__ R,
                          const float* __restrict__ T,
                          float* __restrict__ wout,
                          const int* __restrict__ nz, int E, int N) {
    int e = blockIdx.x * blockDim.x + threadIdx.x;
    if (e >= E) return;
    int is64 = (*nz == 0);
    int n = load_idx(ei, (long long)E + e, is64);
    float w = 1.0f;
    if ((unsigned)n < (unsigned)N) {
        float p0 = src[3 * n + 0], p1 = src[3 * n + 1], p2 = src[3 * n + 2];
        float q0 = tgt[3 * n + 0], q1 = tgt[3 * n + 1], q2 = tgt[3 * n + 2];
        const float* Rn = R + 9 * (long long)n;
        const float* Tn = T + 3 * (long long)n;
        float x0 = Rn[0] * p0 + Rn[1] * p1 + Rn[2] * p2 + Tn[0];
        float x1 = Rn[3] * p0 + Rn[4] * p1 + Rn[5] * p2 + Tn[1];
        float x2 = Rn[6] * p0 + Rn[7] * p1 + Rn[8] * p2 + Tn[2];
        float d0 = x0 - q0, d1 = x1 - q1, d2 = x2 - q2;
        float dd = d0 * d0 + d1 * d1 + d2 * d2;
        w = kSigma2 / (dd + kSigma2);
    }
    wout[e] = w;
}

// ---------------- fallback atomic path (R1 kernels) ----------------

__global__ void k_accum1(const void* __restrict__ ei, const float* __restrict__ src,
                         const float* __restrict__ tgt, float* __restrict__ cnt,
                         float* __restrict__ ssum, float* __restrict__ tsum,
                         const int* __restrict__ nz, int E, int N) {
    int e = blockIdx.x * blockDim.x + threadIdx.x;
    if (e >= E) return;
    int is64 = (*nz == 0);
    int d = load_idx(ei, e, is64);
    int n = load_idx(ei, (long long)E + e, is64);
    if ((unsigned)d >= (unsigned)N || (unsigned)n >= (unsigned)N) return;
    atomicAdd(&cnt[d], 1.0f);
    atomicAdd(&ssum[3 * d + 0], src[3 * n + 0]);
    atomicAdd(&ssum[3 * d + 1], src[3 * n + 1]);
    atomicAdd(&ssum[3 * d + 2], src[3 * n + 2]);
    atomicAdd(&tsum[3 * d + 0], tgt[3 * n + 0]);
    atomicAdd(&tsum[3 * d + 1], tgt[3 * n + 1]);
    atomicAdd(&tsum[3 * d + 2], tgt[3 * n + 2]);
}

__global__ void k_centers(float* __restrict__ cnt, float* __restrict__ ssum,
                          float* __restrict__ tsum, int N) {
    int i = blockIdx.x * blockDim.x + threadIdx.x;
    if (i >= N) return;
    float inv = 1.0f / fmaxf(cnt[i], 1.0f);
    ssum[3 * i + 0] *= inv; ssum[3 * i + 1] *= inv; ssum[3 * i + 2] *= inv;
    tsum[3 * i + 0] *= inv; tsum[3 * i + 1] *= inv; tsum[3 * i + 2] *= inv;
}

__global__ void k_accum2(const void* __restrict__ ei, const float* __restrict__ src,
                         const float* __restrict__ tgt, const float* __restrict__ ew,
                         const float* __restrict__ sc, const float* __restrict__ tc,
                         float* __restrict__ Mm, const int* __restrict__ nz, int E, int N) {
    int e = blockIdx.x * blockDim.x + threadIdx.x;
    if (e >= E) return;
    int is64 = (*nz == 0);
    int d = load_idx(ei, e, is64);
    int n = load_idx(ei, (long long)E + e, is64);
    if ((unsigned)d >= (unsigned)N || (unsigned)n >= (unsigned)N) return;
    float w = ew[e];
    float a0 = (src[3 * n + 0] - sc[3 * d + 0]) * w;
    float a1 = (src[3 * n + 1] - sc[3 * d + 1]) * w;
    float a2 = (src[3 * n + 2] - sc[3 * d + 2]) * w;
    float b0 = tgt[3 * n + 0] - tc[3 * d + 0];
    float b1 = tgt[3 * n + 1] - tc[3 * d + 1];
    float b2 = tgt[3 * n + 2] - tc[3 * d + 2];
    float* Md = Mm + 9 * (long long)d;
    atomicAdd(Md + 0, a0 * b0); atomicAdd(Md + 1, a0 * b1); atomicAdd(Md + 2, a0 * b2);
    atomicAdd(Md + 3, a1 * b0); atomicAdd(Md + 4, a1 * b1); atomicAdd(Md + 5, a1 * b2);
    atomicAdd(Md + 6, a2 * b0); atomicAdd(Md + 7, a2 * b1); atomicAdd(Md + 8, a2 * b2);
}

__global__ void k_kabsch(const float* __restrict__ Mm, const float* __restrict__ sc,
                         const float* __restrict__ tc, float* __restrict__ Rout,
                         float* __restrict__ Tout, int N) {
    int i = blockIdx.x * blockDim.x + threadIdx.x;
    if (i >= N) return;
    double M[3][3];
#pragma unroll
    for (int r = 0; r < 3; ++r)
#pragma unroll
        for (int c = 0; c < 3; ++c)
            M[r][c] = (double)Mm[9 * (long long)i + 3 * r + c];
    double Rm[3][3];
    kabsch_from_M(M, Rm);
    double s0 = sc[3 * i + 0], s1 = sc[3 * i + 1], s2 = sc[3 * i + 2];
    double t0 = tc[3 * i + 0], t1 = tc[3 * i + 1], t2 = tc[3 * i + 2];
#pragma unroll
    for (int r = 0; r < 3; ++r)
#pragma unroll
        for (int c = 0; c < 3; ++c)
            Rout[9 * (long long)i + 3 * r + c] = (float)Rm[r][c];
    Tout[3 * i + 0] = (float)(t0 - (Rm[0][0] * s0 + Rm[0][1] * s1 + Rm[0][2] * s2));
    Tout[3 * i + 1] = (float)(t1 - (Rm[1][0] * s0 + Rm[1][1] * s1 + Rm[1][2] * s2));
    Tout[3 * i + 2] = (float)(t2 - (Rm[2][0] * s0 + Rm[2][1] * s1 + Rm[2][2] * s2));
}

extern "C" void kernel_launch(void* const* d_in, const int* in_sizes, int n_in,
                              void* d_out, int out_size, void* d_ws, size_t ws_size,
                              hipStream_t stream) {
    const float* src = (const float*)d_in[0];
    const float* tgt = (const float*)d_in[1];
    const void* ei = d_in[2];
    const float* ew = (const float*)d_in[3];
    int N = in_sizes[0] / 3;
    int E = in_sizes[3];

    float* out = (float*)d_out;
    float* Rout = out;
    float* Tout = out + (size_t)9 * N;
    float* Wout = out + (size_t)12 * N;

    int eb = (E + 255) / 256;
    int nb = (N + 255) / 256;
    int nb1 = (N + 255) / 256;  // scan1 blocks (must be <= 512)

    // ws layout (sorted path): [nz(1) | cnt(N) | partials(512) | off(N) | cur(N) | pad | sedge(2E)]
    size_t hdr_ints = (size_t)1 + N + 512 + N + N;
    hdr_ints = (hdr_ints + 1) & ~(size_t)1;  // 8B-align sedge
    size_t need = hdr_ints * sizeof(int) + (size_t)E * sizeof(int2);

    if (ws_size >= need && nb1 <= 512) {
        int* nz = (int*)d_ws;
        int* cnt = nz + 1;
        int* partials = cnt + N;
        int* off = partials + 512;
        int* cur = off + N;
        int2* sedge = (int2*)((int*)d_ws + hdr_ints);

        // zero nz + cnt + partials (contiguous prefix)
        hipMemsetAsync(d_ws, 0, (size_t)(1 + N + 512) * sizeof(int), stream);

        k_detect<<<1, 256, 0, stream>>>((const int*)ei, E, nz);
        k_hist<<<eb, 256, 0, stream>>>(ei, cnt, nz, E, N);
        k_scan1<<<nb1, 256, 0, stream>>>(cnt, off, partials, N);
        k_scan2<<<1, 512, 0, stream>>>(partials, nb1);
        k_scan3<<<nb, 256, 0, stream>>>(off, cur, partials, N);
        k_scatter<<<eb, 256, 0, stream>>>(ei, ew, cur, sedge, nz, E, N);
        k_node<<<nb, 256, 0, stream>>>(off, cur, sedge, src, tgt, Rout, Tout, N);
        k_weights<<<eb, 256, 0, stream>>>(ei, src, tgt, Rout, Tout, Wout, nz, E, N);
    } else {
        // fallback: atomic path (R1)
        float* cnt = (float*)d_ws;
        float* ssum = cnt + N;
        float* tsum = ssum + 3 * (size_t)N;
        float* Mm = tsum + 3 * (size_t)N;
        int* nz = (int*)(Mm + 9 * (size_t)N);
        size_t ws_bytes = (size_t)16 * N * sizeof(float) + 16;
        hipMemsetAsync(d_ws, 0, ws_bytes, stream);
        k_detect<<<1, 256, 0, stream>>>((const int*)ei, E, nz);
        k_accum1<<<eb, 256, 0, stream>>>(ei, src, tgt, cnt, ssum, tsum, nz, E, N);
        k_centers<<<nb, 256, 0, stream>>>(cnt, ssum, tsum, N);
        k_accum2<<<eb, 256, 0, stream>>>(ei, src, tgt, ew, ssum, tsum, Mm, nz, E, N);
        k_kabsch<<<nb, 256, 0, stream>>>(Mm, ssum, tsum, Rout, Tout, N);
        k_weights<<<eb, 256, 0, stream>>>(ei, src, tgt, Rout, Tout, Wout, nz, E, N);
    }
}